// Round 1
// baseline (156.621 us; speedup 1.0000x reference)
//
#include <hip/hip_runtime.h>
#include <cstdint>
#include <cstddef>

// ELBO loss: top-256 of gamma -> M = I + D^1/2 Rkk D^1/2 (SPD) -> Cholesky
// -> loss = sum(log Lii) + 0.5*(z.S - (L^-1 t1).(L^-1 t2)) + KL
//
// ws layout (floats): [0,65536) M ; +65536 ind(int256) ; +65792 sqv ;
// +66048 t1 ; +66304 t2 ; +66560 klt ; +66816 zS

#define WAVE_SYNC() asm volatile("s_waitcnt lgkmcnt(0)" ::: "memory")

__device__ __forceinline__ float bcast_lane(float v, int lane) {
  return __int_as_float(__builtin_amdgcn_readlane(__float_as_int(v), lane));
}

// ---------------- K1: exact top-256 select by rank + per-selected scalars ----
__global__ __launch_bounds__(256) void k_topk(
    const float* __restrict__ gamma, const float* __restrict__ sigma2,
    const float* __restrict__ z, const float* __restrict__ p,
    const float* __restrict__ pq, const int* __restrict__ Nptr,
    int* __restrict__ ind, float* __restrict__ sqv,
    float* __restrict__ t1, float* __restrict__ klt) {
  // 8 chunks of 1024 floats, each chunk padded by 8 floats to skew banks
  __shared__ __align__(16) float g[8 * 1032];
  int t = threadIdx.x;
  const float4* ga4 = (const float4*)gamma;
  #pragma unroll
  for (int m = 0; m < 8; ++m) {
    int i = 4 * (t + m * 256);          // element index, multiple of 4
    float4 v = ga4[t + m * 256];
    *(float4*)&g[i + 8 * (i >> 10)] = v; // never crosses a chunk boundary
  }
  __syncthreads();
  int e = blockIdx.x * 32 + (t >> 3);   // element this thread group ranks
  int chunk = t & 7;                     // 1/8th of the scan per thread
  float ge = g[e + 8 * (e >> 10)];
  const float4* g4 = (const float4*)g;
  int i4base = chunk * 258;              // 1032/4 floats per chunk
  int jbase = chunk * 1024;
  int cnt = 0;
  for (int it = 0; it < 256; ++it) {
    float4 v = g4[i4base + it];
    int j = jbase + 4 * it;
    cnt += (v.x > ge || (v.x == ge && (j + 0) < e)) ? 1 : 0;
    cnt += (v.y > ge || (v.y == ge && (j + 1) < e)) ? 1 : 0;
    cnt += (v.z > ge || (v.z == ge && (j + 2) < e)) ? 1 : 0;
    cnt += (v.w > ge || (v.w == ge && (j + 3) < e)) ? 1 : 0;
  }
  cnt += __shfl_xor(cnt, 1);
  cnt += __shfl_xor(cnt, 2);
  cnt += __shfl_xor(cnt, 4);
  if (chunk == 0 && cnt < 256) {
    float u = ge;
    float mask = (u > 0.01f) ? 1.0f : 0.0f;
    float fN = (float)Nptr[0];
    float vals = fN * sigma2[e] * u * mask;
    float sq = sqrtf(vals);
    ind[cnt] = e;
    sqv[cnt] = sq;
    t1[cnt] = sq * z[e];
    float x1 = p[e], x2 = pq[e];
    klt[cnt] = mask * (x2 * (logf(x2) - logf(x1)) +
                       (1.0f - x2) * (logf(1.0f - x2) - logf(1.0f - x1)));
  }
}

// ---------------- K2: VS = Rk.S, build M = I + D^1/2 Rkk D^1/2, and z.S -----
__global__ __launch_bounds__(256) void k_vs(
    const float* __restrict__ R, const float* __restrict__ S,
    const float* __restrict__ z, const int* __restrict__ ind,
    const float* __restrict__ sqv, float* __restrict__ M,
    float* __restrict__ t2, float* __restrict__ zS) {
  __shared__ __align__(16) float row[8192];
  __shared__ float red[4];
  int t = threadIdx.x;
  int b = blockIdx.x;
  if (b < 256) {
    int ridx = ind[b];
    const float4* Rr = (const float4*)(R + (size_t)ridx * 8192);
    const float4* S4 = (const float4*)S;
    float4* row4 = (float4*)row;
    float acc = 0.0f;
    #pragma unroll
    for (int m = 0; m < 8; ++m) {
      float4 v = Rr[t + m * 256];
      row4[t + m * 256] = v;
      float4 s = S4[t + m * 256];
      acc += v.x * s.x + v.y * s.y + v.z * s.z + v.w * s.w;
    }
    #pragma unroll
    for (int o = 32; o > 0; o >>= 1) acc += __shfl_down(acc, o);
    if ((t & 63) == 0) red[t >> 6] = acc;
    __syncthreads();
    float svb = sqv[b];
    if (t == 0) t2[b] = svb * (red[0] + red[1] + red[2] + red[3]);
    int cj = ind[t];
    float rv = row[cj];                    // Rkk[b][t] gathered from LDS
    M[b * 256 + t] = svb * sqv[t] * rv + ((t == b) ? 1.0f : 0.0f);
  } else {
    const float4* z4 = (const float4*)z;
    const float4* S4 = (const float4*)S;
    float acc = 0.0f;
    #pragma unroll
    for (int m = 0; m < 8; ++m) {
      float4 a = z4[t + m * 256];
      float4 s = S4[t + m * 256];
      acc += a.x * s.x + a.y * s.y + a.z * s.z + a.w * s.w;
    }
    #pragma unroll
    for (int o = 32; o > 0; o >>= 1) acc += __shfl_down(acc, o);
    if ((t & 63) == 0) red[t >> 6] = acc;
    __syncthreads();
    if (t == 0) zS[0] = red[0] + red[1] + red[2] + red[3];
  }
}

// ---------------- K3: blocked Cholesky (NB=32) + folded solves + loss -------
__global__ __launch_bounds__(1024, 4) void k_chol(
    float* __restrict__ M, const float* __restrict__ t1w,
    const float* __restrict__ t2w, const float* __restrict__ kltw,
    const float* __restrict__ zSw, float* __restrict__ out) {
  __shared__ __align__(16) float P_cm[32 * 232];  // panel, column-major
  __shared__ __align__(16) float Ld[32 * 36];     // diag tile, padded stride
  __shared__ float rhs1[256], rhs2[256], dv[256];
  __shared__ float idv32[32], y1[32], y2[32];
  __shared__ float red[48];
  int t = threadIdx.x;
  if (t < 256) { rhs1[t] = t1w[t]; rhs2[t] = t2w[t]; }

  for (int K = 0; K < 8; ++K) {
    int base = K * 32;
    __syncthreads();
    // A: load diag tile (1024 threads = 32x32)
    {
      int r = t >> 5, c = t & 31;
      Ld[r * 36 + c] = M[(size_t)(base + r) * 256 + base + c];
    }
    __syncthreads();
    // B: wave0 factors diag tile in registers (readlane broadcasts)
    if (t < 32) {
      int r = t;
      float a[32];
      #pragma unroll
      for (int c = 0; c < 32; ++c) a[c] = Ld[r * 36 + c];
      float myrt = 1.0f, myrinv = 1.0f;
      #pragma unroll
      for (int k = 0; k < 32; ++k) {
        float d = bcast_lane(a[k], k);
        float rinv = rsqrtf(d);
        float rt = d * rinv;
        float m = (r == k) ? rt : a[k] * rinv;
        if (r == k) { myrt = rt; myrinv = rinv; }
        a[k] = m;
        #pragma unroll
        for (int c = k + 1; c < 32; ++c) {
          float lck = bcast_lane(m, c);
          if (r >= c) a[c] -= m * lck;
        }
      }
      #pragma unroll
      for (int c = 0; c < 32; ++c) Ld[r * 36 + c] = a[c];
      dv[base + r] = myrt;
      idv32[r] = myrinv;
    }
    __builtin_amdgcn_wave_barrier();
    WAVE_SYNC();
    // B2: forward-solve the two RHS blocks (lanes 0..31 rhs1, 32..63 rhs2)
    if (t < 64) {
      int r = t & 31;
      float v = (t < 32) ? rhs1[base + r] : rhs2[base + r];
      #pragma unroll
      for (int k = 0; k < 32; ++k) {
        float vk = __shfl(v, (t & 32) | k, 64);
        float yk = vk * idv32[k];
        if (r == k) v = yk;
        else if (r > k) v -= Ld[r * 36 + k] * yk;
      }
      if (t < 32) { rhs1[base + r] = v; y1[r] = v; }
      else        { rhs2[base + r] = v; y2[r] = v; }
    }
    __syncthreads();
    int nb = 224 - base;   // rows below the diag block
    // C: TRSM of the panel rows (one thread per row) + rhs trailing update
    if (t < nb) {
      int gi = base + 32 + t;
      const float4* Mr = (const float4*)(M + (size_t)gi * 256 + base);
      float a[32];
      #pragma unroll
      for (int qq = 0; qq < 8; ++qq) {
        float4 v = Mr[qq];
        a[4*qq] = v.x; a[4*qq+1] = v.y; a[4*qq+2] = v.z; a[4*qq+3] = v.w;
      }
      float x[32];
      #pragma unroll
      for (int c = 0; c < 32; ++c) {
        float s = a[c];
        #pragma unroll
        for (int k = 0; k < c; ++k) s -= x[k] * Ld[c * 36 + k];
        x[c] = s * idv32[c];
      }
      float s1 = 0.0f, s2 = 0.0f;
      #pragma unroll
      for (int k = 0; k < 32; ++k) {
        P_cm[k * 232 + t] = x[k];
        s1 += x[k] * y1[k];
        s2 += x[k] * y2[k];
      }
      rhs1[gi] -= s1;
      rhs2[gi] -= s2;
    }
    __syncthreads();
    // D: rank-32 trailing update of lower-triangle 8x8 blocks
    {
      int nbb = nb >> 3;
      int wv = t >> 6, ln = t & 63;
      int rr = ln >> 3, bcl = ln & 7;
      for (int br = wv; br < nbb; br += 16) {
        int gi = base + 32 + br * 8 + rr;
        float* Mrow = M + (size_t)gi * 256;
        for (int c0 = 0; c0 <= br; c0 += 8) {
          int bc = c0 + bcl;
          if (bc <= br) {
            int gj = base + 32 + bc * 8;
            float4 v0 = *(float4*)(Mrow + gj);
            float4 v1 = *(float4*)(Mrow + gj + 4);
            #pragma unroll
            for (int k = 0; k < 32; ++k) {
              float av = P_cm[k * 232 + br * 8 + rr];
              const float4 b0 = *(const float4*)&P_cm[k * 232 + bc * 8];
              const float4 b1 = *(const float4*)&P_cm[k * 232 + bc * 8 + 4];
              v0.x -= av * b0.x; v0.y -= av * b0.y;
              v0.z -= av * b0.z; v0.w -= av * b0.w;
              v1.x -= av * b1.x; v1.y -= av * b1.y;
              v1.z -= av * b1.z; v1.w -= av * b1.w;
            }
            *(float4*)(Mrow + gj) = v0;
            *(float4*)(Mrow + gj + 4) = v1;
          }
        }
      }
    }
  }
  __syncthreads();
  // Epilogue: logdet/2 = sum log Lii ; q = w1.w2 ; kl ; final loss
  float v1 = 0.0f, v2 = 0.0f, v3 = 0.0f;
  if (t < 256) {
    v1 = logf(dv[t]);
    v2 = rhs1[t] * rhs2[t];
    v3 = kltw[t];
  }
  #pragma unroll
  for (int o = 32; o > 0; o >>= 1) {
    v1 += __shfl_down(v1, o);
    v2 += __shfl_down(v2, o);
    v3 += __shfl_down(v3, o);
  }
  if ((t & 63) == 0) {
    int w = t >> 6;
    red[w] = v1; red[16 + w] = v2; red[32 + w] = v3;
  }
  __syncthreads();
  if (t == 0) {
    float ld = 0.0f, q = 0.0f, kl = 0.0f;
    for (int w = 0; w < 16; ++w) {
      ld += red[w]; q += red[16 + w]; kl += red[32 + w];
    }
    out[0] = ld + 0.5f * (zSw[0] - q) + kl;
  }
}

extern "C" void kernel_launch(void* const* d_in, const int* in_sizes, int n_in,
                              void* d_out, int out_size, void* d_ws, size_t ws_size,
                              hipStream_t stream) {
  const float* R      = (const float*)d_in[0];
  const float* z      = (const float*)d_in[1];
  const float* sigma2 = (const float*)d_in[2];
  const float* p      = (const float*)d_in[3];
  const float* pq     = (const float*)d_in[4];
  const float* gamma  = (const float*)d_in[5];
  const float* S      = (const float*)d_in[6];
  const int*   Nptr   = (const int*)d_in[7];
  float* out = (float*)d_out;

  float* wsf = (float*)d_ws;
  float* M   = wsf;                       // 256*256
  int*   ind = (int*)(wsf + 65536);       // 256
  float* sqv = wsf + 65536 + 256;
  float* t1  = wsf + 65536 + 512;
  float* t2  = wsf + 65536 + 768;
  float* klt = wsf + 65536 + 1024;
  float* zS  = wsf + 65536 + 1280;

  k_topk<<<256, 256, 0, stream>>>(gamma, sigma2, z, p, pq, Nptr,
                                  ind, sqv, t1, klt);
  k_vs<<<257, 256, 0, stream>>>(R, S, z, ind, sqv, M, t2, zS);
  k_chol<<<1, 1024, 0, stream>>>(M, t1, t2, klt, zS, out);
}